// Round 6
// baseline (306.039 us; speedup 1.0000x reference)
//
#include <hip/hip_runtime.h>

#define IMG 512
#define OUT_R 16
#define OUT_C 64
#define HALO 5
#define NVTILE 5         // col-tiles of 16 (80 cols incl. halo+pad)
#define VS 88            // vb row stride in halfs (176B, 16B-aligned)
#define NT 256
#define NSLOTS 64

typedef _Float16 f16x8 __attribute__((ext_vector_type(8)));
typedef _Float16 h2    __attribute__((ext_vector_type(2)));
typedef float    f32x4 __attribute__((ext_vector_type(4)));

static constexpr float GWf[11] = {
    0.00102838f, 0.00759876f, 0.03600077f, 0.10936053f, 0.21300556f,
    0.26601170f, 0.21300556f, 0.10936053f, 0.03600077f, 0.00759876f,
    0.00102838f };

// Banded weight fragment W[i][k] = w[k-i] (A for vertical, B for horizontal).
// Mapping HW-verified by R2/R3/R4 absmax=0: lane(fj,fg) elem b <-> k=8*fg+b,
// i/j = fj. The SAME table serves both stages.
struct WTab { alignas(16) _Float16 v[4][16][8]; };
static constexpr WTab make_wtab() {
    WTab t{};
    for (int g = 0; g < 4; ++g)
        for (int j = 0; j < 16; ++j)
            for (int b = 0; b < 8; ++b) {
                const int d = 8 * g + b - j;
                t.v[g][j][b] = (d >= 0 && d <= 10) ? (_Float16)GWf[d]
                                                   : (_Float16)0.f;
            }
    return t;
}
__device__ constexpr WTab WT = make_wtab();

// Only LDS: vertical-conv output (the vert->horiz transpose) + reduce scratch.
struct SMem {
    _Float16 vb[4][OUT_R][VS];   // 11264 B
    float red[4];
};                               // 11280 B -> LDS never the residency limit

__device__ __forceinline__ h2 cvt_pk(float a, float b) {
#if __has_builtin(__builtin_amdgcn_cvt_pkrtz)
    // builtin returns __fp16x2; bit-identical to _Float16x2 -> reinterpret
    auto r = __builtin_amdgcn_cvt_pkrtz(a, b);
    union { decltype(r) i; h2 o; } u; u.i = r;
    return u.o;
#else
    h2 r; r[0] = (_Float16)a; r[1] = (_Float16)b; return r;
#endif
}

// One vertical col-tile: build B-frags for {x,y,q,p} straight from global
// loads (no LDS staging), 4 MFMAs, scatter D into vb.
__device__ __forceinline__ void vert_tile(
    int tl, int c0, int y0, size_t pbase,
    const float* __restrict__ den, const float* __restrict__ cln,
    int fj, int fg, f16x8 wf, SMem* sm)
{
    const int gc = c0 - HALO + tl * 16 + fj;
    const bool colok = (unsigned)gc < IMG;
    const int rbase = y0 - HALO + 8 * fg;

    float xr[8], yr[8];
#pragma unroll
    for (int b = 0; b < 8; ++b) {
        const int gr = rbase + b;
        // k = 8*fg+b >= 26 rows have zero weight -> skip the load entirely
        const bool ok = colok && ((unsigned)gr < IMG) && (8 * fg + b < 26);
        float xv = 0.f, yv = 0.f;
        if (ok) {
            const size_t idx = pbase + (size_t)gr * IMG + gc;
            xv = den[idx]; yv = cln[idx];
        }
        xr[b] = xv; yr[b] = yv;
    }

    union { f16x8 v; h2 p[4]; } fx, fy, fq, fp;
#pragma unroll
    for (int bb = 0; bb < 4; ++bb) {
        const float x0 = fminf(fmaxf(xr[2 * bb], 0.f), 1.f);      // v_med3
        const float x1 = fminf(fmaxf(xr[2 * bb + 1], 0.f), 1.f);
        const float ya = fminf(fmaxf(yr[2 * bb], 0.f), 1.f);
        const float yb = fminf(fmaxf(yr[2 * bb + 1], 0.f), 1.f);
        const h2 xh = cvt_pk(x0, x1);
        const h2 yh = cvt_pk(ya, yb);
        fx.p[bb] = xh;
        fy.p[bb] = yh;
        fq.p[bb] = xh * xh + yh * yh;    // v_pk_mul + v_pk_fma
        fp.p[bb] = xh * yh;              // v_pk_mul
    }

    const f32x4 zero4 = {0.f, 0.f, 0.f, 0.f};
    const f32x4 a0 = __builtin_amdgcn_mfma_f32_16x16x32_f16(wf, fx.v, zero4, 0, 0, 0);
    const f32x4 a1 = __builtin_amdgcn_mfma_f32_16x16x32_f16(wf, fy.v, zero4, 0, 0, 0);
    const f32x4 a2 = __builtin_amdgcn_mfma_f32_16x16x32_f16(wf, fq.v, zero4, 0, 0, 0);
    const f32x4 a3 = __builtin_amdgcn_mfma_f32_16x16x32_f16(wf, fp.v, zero4, 0, 0, 0);

    const int cc = tl * 16 + fj;
#pragma unroll
    for (int b = 0; b < 4; ++b) {
        const int r = 4 * fg + b;     // D layout: col=lane&15, row=4*(lane>>4)+b
        sm->vb[0][r][cc] = (_Float16)a0[b];
        sm->vb[1][r][cc] = (_Float16)a1[b];
        sm->vb[2][r][cc] = (_Float16)a2[b];
        sm->vb[3][r][cc] = (_Float16)a3[b];
    }
}

__global__ __launch_bounds__(NT, 6)
void ssim_mfma(const float* __restrict__ den, const float* __restrict__ cln,
               double* __restrict__ slots) {
    __shared__ SMem sm;

    const int t    = threadIdx.x;
    const int lane = t & 63;
    const int w    = t >> 6;
    const int fj   = lane & 15;
    const int fg   = lane >> 4;

    // XCD-chunked swizzle (grid % 8 == 0): row-neighbors share halo rows.
    const int bid = blockIdx.x;
    const int chunk = gridDim.x >> 3;
    const int vid = (bid & 7) * chunk + (bid >> 3);

    const int rs    = vid & 31;         // 32 row strips of 16
    const int cs    = (vid >> 5) & 7;   // 8 col strips of 64
    const int plane = vid >> 8;         // 96 planes
    const int c0 = cs * OUT_C;
    const int y0 = rs * OUT_R;
    const size_t pbase = (size_t)plane * (IMG * IMG);

    const f16x8 wf = *reinterpret_cast<const f16x8*>(WT.v[fg][fj]);
    const f32x4 zero4 = {0.f, 0.f, 0.f, 0.f};

    // ---- vertical stage: wave w owns col-tile w; wave 0 also tile 4 ----
    vert_tile(w, c0, y0, pbase, den, cln, fj, fg, wf, &sm);
    if (w == 0)
        vert_tile(4, c0, y0, pbase, den, cln, fj, fg, wf, &sm);
    __syncthreads();

    // ---- horizontal stage (out-tile m = w) + SSIM ----
    float sacc = 0.f;
    {
        f32x4 d[4];
#pragma unroll
        for (int ch = 0; ch < 4; ++ch) {
            const f16x8 af = *reinterpret_cast<const f16x8*>(
                &sm.vb[ch][fj][w * 16 + 8 * fg]);
            d[ch] = __builtin_amdgcn_mfma_f32_16x16x32_f16(af, wf, zero4, 0, 0, 0);
        }
#pragma unroll
        for (int b = 0; b < 4; ++b) {
            const float C1 = 1e-4f, C2 = 9e-4f;
            const float mu1 = d[0][b], mu2 = d[1][b];
            const float qb  = d[2][b], pb  = d[3][b];
            const float mu1s = mu1 * mu1, mu2s = mu2 * mu2, mu12 = mu1 * mu2;
            const float ssum = qb - mu1s - mu2s;
            const float s12  = pb - mu12;
            const float num = fmaf(2.f, mu12, C1) * fmaf(2.f, s12, C2);
            const float dnm = (mu1s + mu2s + C1) * (ssum + C2);
            sacc = fmaf(num, __builtin_amdgcn_rcpf(dnm), sacc);
        }
    }

    // ---- block reduction, one f64 atomic per block into a hashed slot ----
#pragma unroll
    for (int off = 32; off > 0; off >>= 1)
        sacc += __shfl_down(sacc, off, 64);
    if (lane == 0) sm.red[w] = sacc;
    __syncthreads();
    if (t == 0) {
        const float s = sm.red[0] + sm.red[1] + sm.red[2] + sm.red[3];
        atomicAdd(&slots[(size_t)(bid & (NSLOTS - 1)) * 8], (double)s);
    }
}

__global__ void ssim_finalize(const double* __restrict__ slots,
                              float* __restrict__ out, double inv_n) {
    double s = 0.0;
    for (int i = 0; i < NSLOTS; ++i) s += slots[i * 8];
    out[0] = 1.0f - (float)(s * inv_n);
}

extern "C" void kernel_launch(void* const* d_in, const int* in_sizes, int n_in,
                              void* d_out, int out_size, void* d_ws,
                              size_t ws_size, hipStream_t stream) {
    const float* den = (const float*)d_in[0];
    const float* cln = (const float*)d_in[1];
    float* out = (float*)d_out;
    double* slots = (double*)d_ws;

    (void)hipMemsetAsync(d_ws, 0, NSLOTS * 64, stream);

    const int n = in_sizes[0];                  // 32*3*512*512 elements
    const int planes = n / (IMG * IMG);         // 96
    dim3 grid(planes * (IMG / OUT_R) * (IMG / OUT_C));   // 96*32*8 = 24576
    ssim_mfma<<<grid, NT, 0, stream>>>(den, cln, slots);
    ssim_finalize<<<1, 1, 0, stream>>>(slots, out, 1.0 / (double)n);
}